// Round 2
// baseline (251.133 us; speedup 1.0000x reference)
//
#include <hip/hip_runtime.h>
#include <hip/hip_bf16.h>

// Problem dims
#define BD 4096   // batch
#define ID 1024   // input dim
#define HD 1024   // hidden dim
#define KD 2048   // I + H  (concatenated GEMM K)
#define ND 4096   // 4*H    (gate-major GEMM N)

typedef __attribute__((ext_vector_type(8))) __bf16 bf16x8;
typedef __attribute__((ext_vector_type(4))) float f32x4;

static __device__ __forceinline__ unsigned short f2bf(float f) {
  union { float f; unsigned u; } v; v.f = f;
  unsigned u = v.u;
  unsigned r = u + 0x7fffu + ((u >> 16) & 1u);   // round-to-nearest-even
  return (unsigned short)(r >> 16);
}
static __device__ __forceinline__ float bf2f(unsigned short s) {
  union { unsigned u; float f; } v; v.u = ((unsigned)s) << 16;
  return v.f;
}

static __device__ __forceinline__ void gload_lds16(const void* g, void* l) {
  __builtin_amdgcn_global_load_lds(
      (const __attribute__((address_space(1))) void*)g,
      (__attribute__((address_space(3))) void*)l, 16, 0, 0);
}

static __device__ __forceinline__ float fast_sigmoid(float x) {
  return 1.0f / (1.0f + __expf(-x));
}
static __device__ __forceinline__ float fast_tanh(float x) {
  float t = __expf(-2.0f * fabsf(x));
  float r = (1.0f - t) / (1.0f + t);
  return copysignf(r, x);
}

// ---------------- pack kernels: f32 -> bf16, build A=[x|h], Bm=[Wx|Wh] ----------
__global__ void pack_A(const float* __restrict__ x, const float* __restrict__ h,
                       unsigned short* __restrict__ A) {
  int idx = blockIdx.x * blockDim.x + threadIdx.x;  // 2M threads, 4 elems each
  int e = idx << 2;
  int b = e >> 11;        // / 2048
  int k = e & 2047;
  const float* src = (k < ID) ? (x + (size_t)b * ID + k)
                              : (h + (size_t)b * HD + (k - ID));
  float4 v = *reinterpret_cast<const float4*>(src);
  ushort4 o;
  o.x = f2bf(v.x); o.y = f2bf(v.y); o.z = f2bf(v.z); o.w = f2bf(v.w);
  *reinterpret_cast<ushort4*>(A + e) = o;
}

__global__ void pack_B(const float* __restrict__ wxi, const float* __restrict__ wxf,
                       const float* __restrict__ wxg, const float* __restrict__ wxo,
                       const float* __restrict__ whi, const float* __restrict__ whf,
                       const float* __restrict__ whg, const float* __restrict__ who,
                       unsigned short* __restrict__ Bm) {
  int idx = blockIdx.x * blockDim.x + threadIdx.x;  // 2M threads, 4 elems each
  int e = idx << 2;
  int n = e >> 11;
  int k = e & 2047;
  int g = n >> 10, r = n & 1023;
  const float* src;
  if (k < ID) {
    src = (g == 0) ? wxi : (g == 1) ? wxf : (g == 2) ? wxg : wxo;
    src += (size_t)r * ID + k;
  } else {
    src = (g == 0) ? whi : (g == 1) ? whf : (g == 2) ? whg : who;
    src += (size_t)r * HD + (k - ID);
  }
  float4 v = *reinterpret_cast<const float4*>(src);
  ushort4 o;
  o.x = f2bf(v.x); o.y = f2bf(v.y); o.z = f2bf(v.z); o.w = f2bf(v.w);
  *reinterpret_cast<ushort4*>(Bm + e) = o;
}

// ---------------- GEMM: Z[M][N] = A[M][K] * Bm[N][K]^T (bf16 in, bf16 out) -----
// m97 structure: 128x128 tile, BK=32, 4 waves (2x2 of 64x64), global_load_lds w16.
__global__ __launch_bounds__(256, 2) void gemm_bf16(
    const unsigned short* __restrict__ A,   // [4096][2048]
    const unsigned short* __restrict__ Bm,  // [4096][2048]
    unsigned short* __restrict__ Z) {       // [4096][4096]
  __shared__ __attribute__((aligned(16))) unsigned short As[128 * 32];
  __shared__ __attribute__((aligned(16))) unsigned short Bs[128 * 32];

  const int tid  = threadIdx.x;
  const int lane = tid & 63;
  const int w    = tid >> 6;       // wave 0..3
  const int wr   = w >> 1;         // wave row (0/1)
  const int wc   = w & 1;          // wave col (0/1)
  const int m0   = blockIdx.y * 128;
  const int n0   = blockIdx.x * 128;

  f32x4 acc[4][4];
#pragma unroll
  for (int i = 0; i < 4; ++i)
#pragma unroll
    for (int j = 0; j < 4; ++j)
      acc[i][j] = (f32x4){0.f, 0.f, 0.f, 0.f};

  // staging geometry: per wave 2 chunks of 16 rows; lane covers 16B
  const int chunk0 = w * 2;
  const int srow   = lane >> 2;        // 0..15
  const int skq    = (lane & 3) * 8;   // k elem offset 0/8/16/24

  const unsigned short* gA0 = A  + (size_t)(m0 + chunk0 * 16 + srow) * KD + skq;
  const unsigned short* gA1 = A  + (size_t)(m0 + chunk0 * 16 + 16 + srow) * KD + skq;
  const unsigned short* gB0 = Bm + (size_t)(n0 + chunk0 * 16 + srow) * KD + skq;
  const unsigned short* gB1 = Bm + (size_t)(n0 + chunk0 * 16 + 16 + srow) * KD + skq;
  unsigned short* lA0 = &As[(chunk0 * 16) * 32];
  unsigned short* lA1 = &As[(chunk0 * 16 + 16) * 32];
  unsigned short* lB0 = &Bs[(chunk0 * 16) * 32];
  unsigned short* lB1 = &Bs[(chunk0 * 16 + 16) * 32];

  const int kq = (lane >> 4) * 8;       // frag k offset
  const int rA = wr * 64 + (lane & 15); // frag A row in tile
  const int rB = wc * 64 + (lane & 15); // frag B row in tile

  for (int kt = 0; kt < KD; kt += 32) {
    gload_lds16(gA0 + kt, lA0);
    gload_lds16(gA1 + kt, lA1);
    gload_lds16(gB0 + kt, lB0);
    gload_lds16(gB1 + kt, lB1);
    __syncthreads();

    bf16x8 af[4], bfr[4];
#pragma unroll
    for (int mi = 0; mi < 4; ++mi)
      af[mi] = *(const bf16x8*)&As[(rA + mi * 16) * 32 + kq];
#pragma unroll
    for (int ni = 0; ni < 4; ++ni)
      bfr[ni] = *(const bf16x8*)&Bs[(rB + ni * 16) * 32 + kq];
#pragma unroll
    for (int mi = 0; mi < 4; ++mi)
#pragma unroll
      for (int ni = 0; ni < 4; ++ni)
        acc[mi][ni] = __builtin_amdgcn_mfma_f32_16x16x32_bf16(
            af[mi], bfr[ni], acc[mi][ni], 0, 0, 0);
    __syncthreads();
  }

  // C/D layout: col = lane&15, row = (lane>>4)*4 + reg
  const int col0 = n0 + wc * 64 + (lane & 15);
  const int row0 = m0 + wr * 64 + (lane >> 4) * 4;
#pragma unroll
  for (int mi = 0; mi < 4; ++mi)
#pragma unroll
    for (int ni = 0; ni < 4; ++ni)
#pragma unroll
      for (int q = 0; q < 4; ++q) {
        int row = row0 + mi * 16 + q;
        int col = col0 + ni * 16;
        Z[(size_t)row * ND + col] = f2bf(acc[mi][ni][q]);
      }
}

// ---------------- fused peephole-LSTM elementwise epilogue ---------------------
__global__ void lstm_cell(const unsigned short* __restrict__ Z,  // [4096][4096] bf16
                          const float* __restrict__ c,
                          const float* __restrict__ bxi, const float* __restrict__ bhi,
                          const float* __restrict__ bxf, const float* __restrict__ bhf,
                          const float* __restrict__ bxg, const float* __restrict__ bhg,
                          const float* __restrict__ bxo, const float* __restrict__ bho,
                          const float* __restrict__ pci, const float* __restrict__ pcf,
                          const float* __restrict__ pco,
                          float* __restrict__ out) {
  int idx = blockIdx.x * blockDim.x + threadIdx.x;  // 1M threads, 4 elems each
  int e = idx << 2;            // element in [0, 4M)
  int b = e >> 10;
  int r = e & 1023;
  const size_t zrow = (size_t)b * ND;

  ushort4 zi4 = *(const ushort4*)&Z[zrow + r];
  ushort4 zf4 = *(const ushort4*)&Z[zrow + 1024 + r];
  ushort4 zg4 = *(const ushort4*)&Z[zrow + 2048 + r];
  ushort4 zo4 = *(const ushort4*)&Z[zrow + 3072 + r];
  float4 c4   = *(const float4*)&c[e];
  float4 vbxi = *(const float4*)&bxi[r];
  float4 vbhi = *(const float4*)&bhi[r];
  float4 vbxf = *(const float4*)&bxf[r];
  float4 vbhf = *(const float4*)&bhf[r];
  float4 vbxg = *(const float4*)&bxg[r];
  float4 vbhg = *(const float4*)&bhg[r];
  float4 vbxo = *(const float4*)&bxo[r];
  float4 vbho = *(const float4*)&bho[r];
  float4 vpci = *(const float4*)&pci[r];
  float4 vpcf = *(const float4*)&pcf[r];
  float4 vpco = *(const float4*)&pco[r];

  unsigned short ziu[4] = {zi4.x, zi4.y, zi4.z, zi4.w};
  unsigned short zfu[4] = {zf4.x, zf4.y, zf4.z, zf4.w};
  unsigned short zgu[4] = {zg4.x, zg4.y, zg4.z, zg4.w};
  unsigned short zou[4] = {zo4.x, zo4.y, zo4.z, zo4.w};
  float cc[4]  = {c4.x, c4.y, c4.z, c4.w};
  float bi_[4] = {vbxi.x + vbhi.x, vbxi.y + vbhi.y, vbxi.z + vbhi.z, vbxi.w + vbhi.w};
  float bf_[4] = {vbxf.x + vbhf.x, vbxf.y + vbhf.y, vbxf.z + vbhf.z, vbxf.w + vbhf.w};
  float bg_[4] = {vbxg.x + vbhg.x, vbxg.y + vbhg.y, vbxg.z + vbhg.z, vbxg.w + vbhg.w};
  float bo_[4] = {vbxo.x + vbho.x, vbxo.y + vbho.y, vbxo.z + vbho.z, vbxo.w + vbho.w};
  float pi_[4] = {vpci.x, vpci.y, vpci.z, vpci.w};
  float pf_[4] = {vpcf.x, vpcf.y, vpcf.z, vpcf.w};
  float po_[4] = {vpco.x, vpco.y, vpco.z, vpco.w};

  float hn[4], cn[4];
#pragma unroll
  for (int j = 0; j < 4; ++j) {
    float vi = bf2f(ziu[j]) + bi_[j] + pi_[j] * cc[j];
    float vf = bf2f(zfu[j]) + bf_[j] + pf_[j] * cc[j];
    float vg = bf2f(zgu[j]) + bg_[j];
    float vo = bf2f(zou[j]) + bo_[j];
    float ig = fast_sigmoid(vi);
    float fg = fast_sigmoid(vf);
    float gg = fast_tanh(vg);
    float cnext = fg * cc[j] + ig * gg;
    float og = fast_sigmoid(vo + po_[j] * cnext);
    cn[j] = cnext;
    hn[j] = og * fast_tanh(cnext);
  }
  float4 ho = {hn[0], hn[1], hn[2], hn[3]};
  float4 co = {cn[0], cn[1], cn[2], cn[3]};
  *(float4*)&out[e] = ho;
  *(float4*)&out[(size_t)BD * HD + e] = co;
}

// ---------------- launch -------------------------------------------------------
extern "C" void kernel_launch(void* const* d_in, const int* in_sizes, int n_in,
                              void* d_out, int out_size, void* d_ws, size_t ws_size,
                              hipStream_t stream) {
  const float* x      = (const float*)d_in[0];
  const float* h      = (const float*)d_in[1];
  const float* c      = (const float*)d_in[2];
  const float* W_ii_w = (const float*)d_in[3];
  const float* W_ii_b = (const float*)d_in[4];
  const float* W_hi_w = (const float*)d_in[5];
  const float* W_hi_b = (const float*)d_in[6];
  const float* W_ci   = (const float*)d_in[7];
  const float* W_if_w = (const float*)d_in[8];
  const float* W_if_b = (const float*)d_in[9];
  const float* W_hf_w = (const float*)d_in[10];
  const float* W_hf_b = (const float*)d_in[11];
  const float* W_cf   = (const float*)d_in[12];
  const float* W_ig_w = (const float*)d_in[13];
  const float* W_ig_b = (const float*)d_in[14];
  const float* W_hg_w = (const float*)d_in[15];
  const float* W_hg_b = (const float*)d_in[16];
  const float* W_io_w = (const float*)d_in[17];
  const float* W_io_b = (const float*)d_in[18];
  const float* W_ho_w = (const float*)d_in[19];
  const float* W_ho_b = (const float*)d_in[20];
  const float* W_co   = (const float*)d_in[21];

  // ws layout: A bf16 [4096][2048] (16MB) | Bm bf16 [4096][2048] (16MB) | Z bf16 [4096][4096] (32MB)
  unsigned short* Apack = (unsigned short*)d_ws;
  unsigned short* Bpack = Apack + (size_t)BD * KD;
  unsigned short* Zbuf  = Bpack + (size_t)ND * KD;
  float* out = (float*)d_out;

  dim3 blk(256);
  pack_A<<<dim3(8192), blk, 0, stream>>>(x, h, Apack);
  pack_B<<<dim3(8192), blk, 0, stream>>>(W_ii_w, W_if_w, W_ig_w, W_io_w,
                                         W_hi_w, W_hf_w, W_hg_w, W_ho_w, Bpack);
  gemm_bf16<<<dim3(32, 32), blk, 0, stream>>>(Apack, Bpack, Zbuf);
  lstm_cell<<<dim3(4096), blk, 0, stream>>>(Zbuf, c,
      W_ii_b, W_hi_b, W_if_b, W_hf_b, W_ig_b, W_hg_b, W_io_b, W_ho_b,
      W_ci, W_cf, W_co, out);
}

// Round 3
// 234.942 us; speedup vs baseline: 1.0689x; 1.0689x over previous
//
#include <hip/hip_runtime.h>
#include <hip/hip_bf16.h>

// Problem dims
#define BD 4096   // batch
#define ID 1024   // input dim
#define HD 1024   // hidden dim
#define KD 2048   // I + H  (concatenated GEMM K)
#define ND 4096   // 4*H    (gate-major GEMM N)

typedef __attribute__((ext_vector_type(8))) __bf16 bf16x8;
typedef __attribute__((ext_vector_type(4))) float f32x4;

static __device__ __forceinline__ unsigned short f2bf(float f) {
  union { float f; unsigned u; } v; v.f = f;
  unsigned u = v.u;
  unsigned r = u + 0x7fffu + ((u >> 16) & 1u);   // round-to-nearest-even
  return (unsigned short)(r >> 16);
}
static __device__ __forceinline__ float bf2f(unsigned short s) {
  union { unsigned u; float f; } v; v.u = ((unsigned)s) << 16;
  return v.f;
}

static __device__ __forceinline__ void gload_lds16(const void* g, void* l) {
  __builtin_amdgcn_global_load_lds(
      (const __attribute__((address_space(1))) void*)g,
      (__attribute__((address_space(3))) void*)l, 16, 0, 0);
}

static __device__ __forceinline__ float fast_sigmoid(float x) {
  return 1.0f / (1.0f + __expf(-x));
}
static __device__ __forceinline__ float fast_tanh(float x) {
  float t = __expf(-2.0f * fabsf(x));
  float r = (1.0f - t) / (1.0f + t);
  return copysignf(r, x);
}

// ---------------- fused pack kernel: f32 -> bf16, A=[x|h], Bm=[Wx|Wh] ----------
// blocks [0,8192): pack A. blocks [8192,16384): pack Bm.
__global__ void pack_AB(const float* __restrict__ x, const float* __restrict__ h,
                        const float* __restrict__ wxi, const float* __restrict__ wxf,
                        const float* __restrict__ wxg, const float* __restrict__ wxo,
                        const float* __restrict__ whi, const float* __restrict__ whf,
                        const float* __restrict__ whg, const float* __restrict__ who,
                        unsigned short* __restrict__ A, unsigned short* __restrict__ Bm) {
  if (blockIdx.x < 8192) {
    int idx = blockIdx.x * blockDim.x + threadIdx.x;
    int e = idx << 2;
    int b = e >> 11;
    int k = e & 2047;
    const float* src = (k < ID) ? (x + (size_t)b * ID + k)
                                : (h + (size_t)b * HD + (k - ID));
    float4 v = *reinterpret_cast<const float4*>(src);
    ushort4 o;
    o.x = f2bf(v.x); o.y = f2bf(v.y); o.z = f2bf(v.z); o.w = f2bf(v.w);
    *reinterpret_cast<ushort4*>(A + e) = o;
  } else {
    int idx = (blockIdx.x - 8192) * blockDim.x + threadIdx.x;
    int e = idx << 2;
    int n = e >> 11;
    int k = e & 2047;
    int g = n >> 10, r = n & 1023;
    const float* src;
    if (k < ID) {
      src = (g == 0) ? wxi : (g == 1) ? wxf : (g == 2) ? wxg : wxo;
      src += (size_t)r * ID + k;
    } else {
      src = (g == 0) ? whi : (g == 1) ? whf : (g == 2) ? whg : who;
      src += (size_t)r * HD + (k - ID);
    }
    float4 v = *reinterpret_cast<const float4*>(src);
    ushort4 o;
    o.x = f2bf(v.x); o.y = f2bf(v.y); o.z = f2bf(v.z); o.w = f2bf(v.w);
    *reinterpret_cast<ushort4*>(Bm + e) = o;
  }
}

// ---------------- GEMM: Z[M][N] = A[M][K] * Bm[N][K]^T ------------------------
// 256x256 tile, BK=64, 8 waves (2Mx4N), 2x double-buffered LDS (128KB),
// 4 MFMA-phases per K-tile, counted-latency staging (issue phase 0, wait at
// tile boundary), XOR-swizzled LDS (conflict-free ds_read_b128), setprio,
// bijective XCD blockIdx swizzle.
__global__ __launch_bounds__(512, 2) void gemm_bf16(
    const unsigned short* __restrict__ A,   // [4096][2048]
    const unsigned short* __restrict__ Bm,  // [4096][2048]
    unsigned short* __restrict__ Z) {       // [4096][4096]
  // LDS: A: [2 bufs][256 rows][64 cols] bf16 at 0..64KB; B same at 64..128KB.
  // Within a row, 8 chunks of 8 elems (16B); chunk index stored XOR (row&7).
  __shared__ __attribute__((aligned(16))) unsigned short lds[65536];

  const int tid  = threadIdx.x;     // 0..511
  const int lane = tid & 63;
  const int w    = tid >> 6;        // wave 0..7
  const int wr   = w >> 2;          // 0..1  (wave row: 128 rows each)
  const int wc   = w & 3;           // 0..3  (wave col: 64 cols each)

  // XCD-aware swizzle: 256 blocks, 8 XCDs, 32 contiguous per XCD (bijective).
  const int bid = blockIdx.x;
  const int swz = (bid & 7) * 32 + (bid >> 3);
  const int m0  = (swz >> 4) * 256;
  const int n0  = (swz & 15) * 256;

  f32x4 acc[8][4];
#pragma unroll
  for (int i = 0; i < 8; ++i)
#pragma unroll
    for (int j = 0; j < 4; ++j)
      acc[i][j] = (f32x4){0.f, 0.f, 0.f, 0.f};

  // per-lane swizzled read offsets (elements)
  const int sw  = lane & 7;
  const int rA0 = (wr * 128 + (lane & 15)) * 64;
  const int rB0 = (wc * 64  + (lane & 15)) * 64;
  const int offk0 = (((lane >> 4)    ) ^ sw) * 8;
  const int offk1 = (((lane >> 4) + 4) ^ sw) * 8;

  unsigned short* ldsA = lds;           // + buf*16384
  unsigned short* ldsB = lds + 32768;   // + buf*16384

  // stage one K-tile (A 256x64 + B 256x64) into buffer `buf`.
  // Linear LDS dest (wave-uniform base + lane*16B); inverse-swizzled global src.
  auto stage = [&](int buf, int kt) {
#pragma unroll
    for (int j = 0; j < 4; ++j) {
      int ci  = j * 512 + tid;          // 16B chunk index, 0..2047
      int row = ci >> 3;                // 0..255
      int sc  = (ci & 7) ^ (row & 7);   // inverse-swizzled source chunk
      const unsigned short* gA = A  + (size_t)(m0 + row) * KD + kt + sc * 8;
      const unsigned short* gB = Bm + (size_t)(n0 + row) * KD + kt + sc * 8;
      unsigned short* lA = ldsA + buf * 16384 + (j * 512 + (tid & ~63)) * 8;
      unsigned short* lB = ldsB + buf * 16384 + (j * 512 + (tid & ~63)) * 8;
      gload_lds16(gA, lA);
      gload_lds16(gB, lB);
    }
  };

  stage(0, 0);   // prologue: tile 0 -> buf 0

  for (int T = 0; T < 32; ++T) {
    const int buf = T & 1;
    const unsigned short* pA = ldsA + buf * 16384;
    const unsigned short* pB = ldsB + buf * 16384;

    // tile boundary: this wave's stages for buf must have landed; then align.
    asm volatile("s_waitcnt vmcnt(0)" ::: "memory");
    __builtin_amdgcn_s_barrier();
    __builtin_amdgcn_sched_barrier(0);

    // B fragments for the whole tile (8 x ds_read_b128)
    bf16x8 bfr[4][2];
#pragma unroll
    for (int ni = 0; ni < 4; ++ni) {
      bfr[ni][0] = *(const bf16x8*)(pB + rB0 + ni * 1024 + offk0);
      bfr[ni][1] = *(const bf16x8*)(pB + rB0 + ni * 1024 + offk1);
    }

    // issue next tile's stages early (latency hidden under 4 MFMA phases)
    if (T < 31) stage(buf ^ 1, (T + 1) * 64);
    __builtin_amdgcn_sched_barrier(0);

    // 4 phases: mi-pair p, 16 MFMA each
#pragma unroll
    for (int p = 0; p < 4; ++p) {
      bf16x8 af[2][2];
#pragma unroll
      for (int i = 0; i < 2; ++i) {
        af[i][0] = *(const bf16x8*)(pA + rA0 + (2 * p + i) * 1024 + offk0);
        af[i][1] = *(const bf16x8*)(pA + rA0 + (2 * p + i) * 1024 + offk1);
      }
      __builtin_amdgcn_s_setprio(1);
#pragma unroll
      for (int i = 0; i < 2; ++i)
#pragma unroll
        for (int ni = 0; ni < 4; ++ni)
#pragma unroll
          for (int kk = 0; kk < 2; ++kk)
            acc[2 * p + i][ni] = __builtin_amdgcn_mfma_f32_16x16x32_bf16(
                af[i][kk], bfr[ni][kk], acc[2 * p + i][ni], 0, 0, 0);
      __builtin_amdgcn_s_setprio(0);
      __builtin_amdgcn_s_barrier();
    }
  }

  // C/D layout: col = lane&15, row = (lane>>4)*4 + q  (verified round 0)
  const int col0 = n0 + wc * 64 + (lane & 15);
  const int row0 = m0 + wr * 128 + (lane >> 4) * 4;
#pragma unroll
  for (int mi = 0; mi < 8; ++mi)
#pragma unroll
    for (int ni = 0; ni < 4; ++ni)
#pragma unroll
      for (int q = 0; q < 4; ++q)
        Z[(size_t)(row0 + mi * 16 + q) * ND + col0 + ni * 16] =
            f2bf(acc[mi][ni][q]);
}

// ---------------- fused peephole-LSTM elementwise epilogue ---------------------
__global__ void lstm_cell(const unsigned short* __restrict__ Z,  // [4096][4096] bf16
                          const float* __restrict__ c,
                          const float* __restrict__ bxi, const float* __restrict__ bhi,
                          const float* __restrict__ bxf, const float* __restrict__ bhf,
                          const float* __restrict__ bxg, const float* __restrict__ bhg,
                          const float* __restrict__ bxo, const float* __restrict__ bho,
                          const float* __restrict__ pci, const float* __restrict__ pcf,
                          const float* __restrict__ pco,
                          float* __restrict__ out) {
  int idx = blockIdx.x * blockDim.x + threadIdx.x;  // 1M threads, 4 elems each
  int e = idx << 2;            // element in [0, 4M)
  int b = e >> 10;
  int r = e & 1023;
  const size_t zrow = (size_t)b * ND;

  ushort4 zi4 = *(const ushort4*)&Z[zrow + r];
  ushort4 zf4 = *(const ushort4*)&Z[zrow + 1024 + r];
  ushort4 zg4 = *(const ushort4*)&Z[zrow + 2048 + r];
  ushort4 zo4 = *(const ushort4*)&Z[zrow + 3072 + r];
  float4 c4   = *(const float4*)&c[e];
  float4 vbxi = *(const float4*)&bxi[r];
  float4 vbhi = *(const float4*)&bhi[r];
  float4 vbxf = *(const float4*)&bxf[r];
  float4 vbhf = *(const float4*)&bhf[r];
  float4 vbxg = *(const float4*)&bxg[r];
  float4 vbhg = *(const float4*)&bhg[r];
  float4 vbxo = *(const float4*)&bxo[r];
  float4 vbho = *(const float4*)&bho[r];
  float4 vpci = *(const float4*)&pci[r];
  float4 vpcf = *(const float4*)&pcf[r];
  float4 vpco = *(const float4*)&pco[r];

  unsigned short ziu[4] = {zi4.x, zi4.y, zi4.z, zi4.w};
  unsigned short zfu[4] = {zf4.x, zf4.y, zf4.z, zf4.w};
  unsigned short zgu[4] = {zg4.x, zg4.y, zg4.z, zg4.w};
  unsigned short zou[4] = {zo4.x, zo4.y, zo4.z, zo4.w};
  float cc[4]  = {c4.x, c4.y, c4.z, c4.w};
  float bi_[4] = {vbxi.x + vbhi.x, vbxi.y + vbhi.y, vbxi.z + vbhi.z, vbxi.w + vbhi.w};
  float bf_[4] = {vbxf.x + vbhf.x, vbxf.y + vbhf.y, vbxf.z + vbhf.z, vbxf.w + vbhf.w};
  float bg_[4] = {vbxg.x + vbhg.x, vbxg.y + vbhg.y, vbxg.z + vbhg.z, vbxg.w + vbhg.w};
  float bo_[4] = {vbxo.x + vbho.x, vbxo.y + vbho.y, vbxo.z + vbho.z, vbxo.w + vbho.w};
  float pi_[4] = {vpci.x, vpci.y, vpci.z, vpci.w};
  float pf_[4] = {vpcf.x, vpcf.y, vpcf.z, vpcf.w};
  float po_[4] = {vpco.x, vpco.y, vpco.z, vpco.w};

  float hn[4], cn[4];
#pragma unroll
  for (int j = 0; j < 4; ++j) {
    float vi = bf2f(ziu[j]) + bi_[j] + pi_[j] * cc[j];
    float vf = bf2f(zfu[j]) + bf_[j] + pf_[j] * cc[j];
    float vg = bf2f(zgu[j]) + bg_[j];
    float vo = bf2f(zou[j]) + bo_[j];
    float ig = fast_sigmoid(vi);
    float fg = fast_sigmoid(vf);
    float gg = fast_tanh(vg);
    float cnext = fg * cc[j] + ig * gg;
    float og = fast_sigmoid(vo + po_[j] * cnext);
    cn[j] = cnext;
    hn[j] = og * fast_tanh(cnext);
  }
  float4 ho = {hn[0], hn[1], hn[2], hn[3]};
  float4 co = {cn[0], cn[1], cn[2], cn[3]};
  *(float4*)&out[e] = ho;
  *(float4*)&out[(size_t)BD * HD + e] = co;
}

// ---------------- launch -------------------------------------------------------
extern "C" void kernel_launch(void* const* d_in, const int* in_sizes, int n_in,
                              void* d_out, int out_size, void* d_ws, size_t ws_size,
                              hipStream_t stream) {
  const float* x      = (const float*)d_in[0];
  const float* h      = (const float*)d_in[1];
  const float* c      = (const float*)d_in[2];
  const float* W_ii_w = (const float*)d_in[3];
  const float* W_ii_b = (const float*)d_in[4];
  const float* W_hi_w = (const float*)d_in[5];
  const float* W_hi_b = (const float*)d_in[6];
  const float* W_ci   = (const float*)d_in[7];
  const float* W_if_w = (const float*)d_in[8];
  const float* W_if_b = (const float*)d_in[9];
  const float* W_hf_w = (const float*)d_in[10];
  const float* W_hf_b = (const float*)d_in[11];
  const float* W_cf   = (const float*)d_in[12];
  const float* W_ig_w = (const float*)d_in[13];
  const float* W_ig_b = (const float*)d_in[14];
  const float* W_hg_w = (const float*)d_in[15];
  const float* W_hg_b = (const float*)d_in[16];
  const float* W_io_w = (const float*)d_in[17];
  const float* W_io_b = (const float*)d_in[18];
  const float* W_ho_w = (const float*)d_in[19];
  const float* W_ho_b = (const float*)d_in[20];
  const float* W_co   = (const float*)d_in[21];

  // ws: A bf16 [4096][2048] (16MB) | Bm bf16 [4096][2048] (16MB) | Z bf16 [4096][4096] (32MB)
  unsigned short* Apack = (unsigned short*)d_ws;
  unsigned short* Bpack = Apack + (size_t)BD * KD;
  unsigned short* Zbuf  = Bpack + (size_t)ND * KD;
  float* out = (float*)d_out;

  pack_AB<<<dim3(16384), dim3(256), 0, stream>>>(
      x, h, W_ii_w, W_if_w, W_ig_w, W_io_w, W_hi_w, W_hf_w, W_hg_w, W_ho_w,
      Apack, Bpack);
  gemm_bf16<<<dim3(256), dim3(512), 0, stream>>>(Apack, Bpack, Zbuf);
  lstm_cell<<<dim3(4096), dim3(256), 0, stream>>>(Zbuf, c,
      W_ii_b, W_hi_b, W_if_b, W_hf_b, W_ig_b, W_hg_b, W_io_b, W_ho_b,
      W_ci, W_cf, W_co, out);
}

// Round 4
// 234.136 us; speedup vs baseline: 1.0726x; 1.0034x over previous
//
#include <hip/hip_runtime.h>
#include <hip/hip_bf16.h>

// Problem dims
#define BD 4096   // batch
#define ID 1024   // input dim
#define HD 1024   // hidden dim
#define KD 2048   // I + H  (concatenated GEMM K)
#define ND 4096   // 4*H    (gate-major GEMM N)

typedef __attribute__((ext_vector_type(8))) __bf16 bf16x8;
typedef __attribute__((ext_vector_type(4))) float f32x4;

static __device__ __forceinline__ unsigned short f2bf(float f) {
  union { float f; unsigned u; } v; v.f = f;
  unsigned u = v.u;
  unsigned r = u + 0x7fffu + ((u >> 16) & 1u);   // round-to-nearest-even
  return (unsigned short)(r >> 16);
}
static __device__ __forceinline__ float bf2f(unsigned short s) {
  union { unsigned u; float f; } v; v.u = ((unsigned)s) << 16;
  return v.f;
}

static __device__ __forceinline__ void gload_lds16(const void* g, void* l) {
  __builtin_amdgcn_global_load_lds(
      (const __attribute__((address_space(1))) void*)g,
      (__attribute__((address_space(3))) void*)l, 16, 0, 0);
}

static __device__ __forceinline__ float fast_sigmoid(float x) {
  return 1.0f / (1.0f + __expf(-x));
}
static __device__ __forceinline__ float fast_tanh(float x) {
  float t = __expf(-2.0f * fabsf(x));
  float r = (1.0f - t) / (1.0f + t);
  return copysignf(r, x);
}

// ---------------- fused pack kernel: f32 -> bf16, A=[x|h], Bm=[Wx|Wh] ----------
__global__ void pack_AB(const float* __restrict__ x, const float* __restrict__ h,
                        const float* __restrict__ wxi, const float* __restrict__ wxf,
                        const float* __restrict__ wxg, const float* __restrict__ wxo,
                        const float* __restrict__ whi, const float* __restrict__ whf,
                        const float* __restrict__ whg, const float* __restrict__ who,
                        unsigned short* __restrict__ A, unsigned short* __restrict__ Bm) {
  if (blockIdx.x < 8192) {
    int idx = blockIdx.x * blockDim.x + threadIdx.x;
    int e = idx << 2;
    int b = e >> 11;
    int k = e & 2047;
    const float* src = (k < ID) ? (x + (size_t)b * ID + k)
                                : (h + (size_t)b * HD + (k - ID));
    float4 v = *reinterpret_cast<const float4*>(src);
    ushort4 o;
    o.x = f2bf(v.x); o.y = f2bf(v.y); o.z = f2bf(v.z); o.w = f2bf(v.w);
    *reinterpret_cast<ushort4*>(A + e) = o;
  } else {
    int idx = (blockIdx.x - 8192) * blockDim.x + threadIdx.x;
    int e = idx << 2;
    int n = e >> 11;
    int k = e & 2047;
    int g = n >> 10, r = n & 1023;
    const float* src;
    if (k < ID) {
      src = (g == 0) ? wxi : (g == 1) ? wxf : (g == 2) ? wxg : wxo;
      src += (size_t)r * ID + k;
    } else {
      src = (g == 0) ? whi : (g == 1) ? whf : (g == 2) ? whg : who;
      src += (size_t)r * HD + (k - ID);
    }
    float4 v = *reinterpret_cast<const float4*>(src);
    ushort4 o;
    o.x = f2bf(v.x); o.y = f2bf(v.y); o.z = f2bf(v.z); o.w = f2bf(v.w);
    *reinterpret_cast<ushort4*>(Bm + e) = o;
  }
}

// ---------------- GEMM: Z[M][N] = A[M][K] * Bm[N][K]^T ------------------------
// 256x256 tile, BK=64, 8 waves (2Mx4N), double-buffered swizzled LDS, 4 MFMA
// phases per tile, quantum-staggered staging with COUNTED vmcnt (T3+T4):
//   quanta per tile: QB (4 loads, all B) -> phase 0;  QA_p (1 load, A rows
//   {32p..}+{128+32p..}) -> phase p.  Boundary waits vmcnt(3), inter-phase
//   vmcnt(7); peeled last tile uses vmcnt(2)/(1)/(0).
__global__ __launch_bounds__(512, 2) void gemm_bf16(
    const unsigned short* __restrict__ A,   // [4096][2048]
    const unsigned short* __restrict__ Bm,  // [4096][2048]
    unsigned short* __restrict__ Z) {       // [4096][4096]
  __shared__ __attribute__((aligned(16))) unsigned short lds[65536];

  const int tid  = threadIdx.x;     // 0..511
  const int lane = tid & 63;
  const int w    = tid >> 6;        // wave 0..7
  const int wr   = w >> 2;          // 0..1  (wave row: 128 rows)
  const int wc   = w & 3;           // 0..3  (wave col: 64 cols)

  // XCD-aware swizzle: 256 blocks, 8 XCDs, 32 contiguous per XCD (bijective).
  const int bid = blockIdx.x;
  const int swz = (bid & 7) * 32 + (bid >> 3);
  const int m0  = (swz >> 4) * 256;
  const int n0  = (swz & 15) * 256;

  f32x4 acc[8][4];
#pragma unroll
  for (int i = 0; i < 8; ++i)
#pragma unroll
    for (int j = 0; j < 4; ++j)
      acc[i][j] = (f32x4){0.f, 0.f, 0.f, 0.f};

  // per-lane swizzled read offsets (elements); slot = chunk ^ (row&7)
  const int sw  = lane & 7;
  const int rA0 = (wr * 128 + (lane & 15)) * 64;
  const int rB0 = (wc * 64  + (lane & 15)) * 64;
  const int offk0 = (((lane >> 4)    ) ^ sw) * 8;
  const int offk1 = (((lane >> 4) + 4) ^ sw) * 8;

  unsigned short* ldsA = lds;           // [2][256][64]
  unsigned short* ldsB = lds + 32768;   // [2][256][64]

  // QB: all 256 B rows (4 x gload_lds16 per thread)
  auto stageB = [&](int buf, int kt) {
#pragma unroll
    for (int q = 0; q < 4; ++q) {
      int ci  = q * 512 + tid;          // 16B chunk index 0..2047
      int row = ci >> 3;
      int sc  = (ci & 7) ^ (row & 7);   // inverse-swizzled source chunk
      gload_lds16(Bm + (size_t)(n0 + row) * KD + kt + sc * 8,
                  ldsB + buf * 16384 + (q * 512 + w * 64) * 8);
    }
  };
  // QA_p: A rows {p*32..p*32+31} u {128+p*32..} (1 x gload_lds16 per thread)
  auto stageA = [&](int buf, int kt, int p) {
    int half = tid >> 8;                // wave-uniform (w>>2)
    int idx  = tid & 255;
    int row  = half * 128 + p * 32 + (idx >> 3);
    int sc   = (idx & 7) ^ ((idx >> 3) & 7);
    gload_lds16(A + (size_t)(m0 + row) * KD + kt + sc * 8,
                ldsA + buf * 16384 + (half * 1024 + p * 256 + (w & 3) * 64) * 8);
  };

  // prologue: full tile 0, in quantum order (QB,QA0 oldest)
  stageB(0, 0);
  stageA(0, 0, 0);
  stageA(0, 0, 1);
  stageA(0, 0, 2);
  stageA(0, 0, 3);

  bf16x8 bfr[4][2];

  for (int T = 0; T < 31; ++T) {
    const int buf = T & 1;
    const unsigned short* pA = ldsA + buf * 16384;
    const unsigned short* pB = ldsB + buf * 16384;
    const int ktn = (T + 1) * 64;

    // boundary: QB(T)+QA0(T) landed; QA1-3(T) may remain in flight
    asm volatile("s_waitcnt vmcnt(3)" ::: "memory");
    __builtin_amdgcn_s_barrier();
    __builtin_amdgcn_sched_barrier(0);

#pragma unroll
    for (int p = 0; p < 4; ++p) {
      if (p == 0) {
#pragma unroll
        for (int ni = 0; ni < 4; ++ni) {
          bfr[ni][0] = *(const bf16x8*)(pB + rB0 + ni * 1024 + offk0);
          bfr[ni][1] = *(const bf16x8*)(pB + rB0 + ni * 1024 + offk1);
        }
      }
      bf16x8 af[2][2];
#pragma unroll
      for (int i = 0; i < 2; ++i) {
        af[i][0] = *(const bf16x8*)(pA + rA0 + (2 * p + i) * 1024 + offk0);
        af[i][1] = *(const bf16x8*)(pA + rA0 + (2 * p + i) * 1024 + offk1);
      }
      // issue next tile's quanta (into buf^1) under this phase's MFMA
      if (p == 0) { stageB(buf ^ 1, ktn); stageA(buf ^ 1, ktn, 0); }
      else        { stageA(buf ^ 1, ktn, p); }
      __builtin_amdgcn_sched_barrier(0);

      __builtin_amdgcn_s_setprio(1);
#pragma unroll
      for (int i = 0; i < 2; ++i)
#pragma unroll
        for (int ni = 0; ni < 4; ++ni)
#pragma unroll
          for (int kk = 0; kk < 2; ++kk)
            acc[2 * p + i][ni] = __builtin_amdgcn_mfma_f32_16x16x32_bf16(
                af[i][kk], bfr[ni][kk], acc[2 * p + i][ni], 0, 0, 0);
      __builtin_amdgcn_s_setprio(0);

      if (p < 3) {  // retire exactly QA_{p+1}(T); keep 7 newer in flight
        asm volatile("s_waitcnt vmcnt(7)" ::: "memory");
        __builtin_amdgcn_s_barrier();
      }
    }
  }

  // peeled last tile (T=31, buf=1): no new issues -> tight waits
  {
    const unsigned short* pA = ldsA + 16384;
    const unsigned short* pB = ldsB + 16384;

    asm volatile("s_waitcnt vmcnt(3)" ::: "memory");
    __builtin_amdgcn_s_barrier();
    __builtin_amdgcn_sched_barrier(0);

#pragma unroll
    for (int p = 0; p < 4; ++p) {
      if (p == 0) {
#pragma unroll
        for (int ni = 0; ni < 4; ++ni) {
          bfr[ni][0] = *(const bf16x8*)(pB + rB0 + ni * 1024 + offk0);
          bfr[ni][1] = *(const bf16x8*)(pB + rB0 + ni * 1024 + offk1);
        }
      }
      bf16x8 af[2][2];
#pragma unroll
      for (int i = 0; i < 2; ++i) {
        af[i][0] = *(const bf16x8*)(pA + rA0 + (2 * p + i) * 1024 + offk0);
        af[i][1] = *(const bf16x8*)(pA + rA0 + (2 * p + i) * 1024 + offk1);
      }
      __builtin_amdgcn_s_setprio(1);
#pragma unroll
      for (int i = 0; i < 2; ++i)
#pragma unroll
        for (int ni = 0; ni < 4; ++ni)
#pragma unroll
          for (int kk = 0; kk < 2; ++kk)
            acc[2 * p + i][ni] = __builtin_amdgcn_mfma_f32_16x16x32_bf16(
                af[i][kk], bfr[ni][kk], acc[2 * p + i][ni], 0, 0, 0);
      __builtin_amdgcn_s_setprio(0);

      if (p == 0) { asm volatile("s_waitcnt vmcnt(2)" ::: "memory"); __builtin_amdgcn_s_barrier(); }
      if (p == 1) { asm volatile("s_waitcnt vmcnt(1)" ::: "memory"); __builtin_amdgcn_s_barrier(); }
      if (p == 2) { asm volatile("s_waitcnt vmcnt(0)" ::: "memory"); __builtin_amdgcn_s_barrier(); }
    }
  }

  // C/D layout: col = lane&15, row = (lane>>4)*4 + q
  const int col0 = n0 + wc * 64 + (lane & 15);
  const int row0 = m0 + wr * 128 + (lane >> 4) * 4;
#pragma unroll
  for (int mi = 0; mi < 8; ++mi)
#pragma unroll
    for (int ni = 0; ni < 4; ++ni)
#pragma unroll
      for (int q = 0; q < 4; ++q)
        Z[(size_t)(row0 + mi * 16 + q) * ND + col0 + ni * 16] =
            f2bf(acc[mi][ni][q]);
}

// ---------------- fused peephole-LSTM elementwise epilogue ---------------------
__global__ void lstm_cell(const unsigned short* __restrict__ Z,  // [4096][4096] bf16
                          const float* __restrict__ c,
                          const float* __restrict__ bxi, const float* __restrict__ bhi,
                          const float* __restrict__ bxf, const float* __restrict__ bhf,
                          const float* __restrict__ bxg, const float* __restrict__ bhg,
                          const float* __restrict__ bxo, const float* __restrict__ bho,
                          const float* __restrict__ pci, const float* __restrict__ pcf,
                          const float* __restrict__ pco,
                          float* __restrict__ out) {
  int idx = blockIdx.x * blockDim.x + threadIdx.x;  // 1M threads, 4 elems each
  int e = idx << 2;            // element in [0, 4M)
  int b = e >> 10;
  int r = e & 1023;
  const size_t zrow = (size_t)b * ND;

  ushort4 zi4 = *(const ushort4*)&Z[zrow + r];
  ushort4 zf4 = *(const ushort4*)&Z[zrow + 1024 + r];
  ushort4 zg4 = *(const ushort4*)&Z[zrow + 2048 + r];
  ushort4 zo4 = *(const ushort4*)&Z[zrow + 3072 + r];
  float4 c4   = *(const float4*)&c[e];
  float4 vbxi = *(const float4*)&bxi[r];
  float4 vbhi = *(const float4*)&bhi[r];
  float4 vbxf = *(const float4*)&bxf[r];
  float4 vbhf = *(const float4*)&bhf[r];
  float4 vbxg = *(const float4*)&bxg[r];
  float4 vbhg = *(const float4*)&bhg[r];
  float4 vbxo = *(const float4*)&bxo[r];
  float4 vbho = *(const float4*)&bho[r];
  float4 vpci = *(const float4*)&pci[r];
  float4 vpcf = *(const float4*)&pcf[r];
  float4 vpco = *(const float4*)&pco[r];

  unsigned short ziu[4] = {zi4.x, zi4.y, zi4.z, zi4.w};
  unsigned short zfu[4] = {zf4.x, zf4.y, zf4.z, zf4.w};
  unsigned short zgu[4] = {zg4.x, zg4.y, zg4.z, zg4.w};
  unsigned short zou[4] = {zo4.x, zo4.y, zo4.z, zo4.w};
  float cc[4]  = {c4.x, c4.y, c4.z, c4.w};
  float bi_[4] = {vbxi.x + vbhi.x, vbxi.y + vbhi.y, vbxi.z + vbhi.z, vbxi.w + vbhi.w};
  float bf_[4] = {vbxf.x + vbhf.x, vbxf.y + vbhf.y, vbxf.z + vbhf.z, vbxf.w + vbhf.w};
  float bg_[4] = {vbxg.x + vbhg.x, vbxg.y + vbhg.y, vbxg.z + vbhg.z, vbxg.w + vbhg.w};
  float bo_[4] = {vbxo.x + vbho.x, vbxo.y + vbho.y, vbxo.z + vbho.z, vbxo.w + vbho.w};
  float pi_[4] = {vpci.x, vpci.y, vpci.z, vpci.w};
  float pf_[4] = {vpcf.x, vpcf.y, vpcf.z, vpcf.w};
  float po_[4] = {vpco.x, vpco.y, vpco.z, vpco.w};

  float hn[4], cn[4];
#pragma unroll
  for (int j = 0; j < 4; ++j) {
    float vi = bf2f(ziu[j]) + bi_[j] + pi_[j] * cc[j];
    float vf = bf2f(zfu[j]) + bf_[j] + pf_[j] * cc[j];
    float vg = bf2f(zgu[j]) + bg_[j];
    float vo = bf2f(zou[j]) + bo_[j];
    float ig = fast_sigmoid(vi);
    float fg = fast_sigmoid(vf);
    float gg = fast_tanh(vg);
    float cnext = fg * cc[j] + ig * gg;
    float og = fast_sigmoid(vo + po_[j] * cnext);
    cn[j] = cnext;
    hn[j] = og * fast_tanh(cnext);
  }
  float4 ho = {hn[0], hn[1], hn[2], hn[3]};
  float4 co = {cn[0], cn[1], cn[2], cn[3]};
  *(float4*)&out[e] = ho;
  *(float4*)&out[(size_t)BD * HD + e] = co;
}

// ---------------- launch -------------------------------------------------------
extern "C" void kernel_launch(void* const* d_in, const int* in_sizes, int n_in,
                              void* d_out, int out_size, void* d_ws, size_t ws_size,
                              hipStream_t stream) {
  const float* x      = (const float*)d_in[0];
  const float* h      = (const float*)d_in[1];
  const float* c      = (const float*)d_in[2];
  const float* W_ii_w = (const float*)d_in[3];
  const float* W_ii_b = (const float*)d_in[4];
  const float* W_hi_w = (const float*)d_in[5];
  const float* W_hi_b = (const float*)d_in[6];
  const float* W_ci   = (const float*)d_in[7];
  const float* W_if_w = (const float*)d_in[8];
  const float* W_if_b = (const float*)d_in[9];
  const float* W_hf_w = (const float*)d_in[10];
  const float* W_hf_b = (const float*)d_in[11];
  const float* W_cf   = (const float*)d_in[12];
  const float* W_ig_w = (const float*)d_in[13];
  const float* W_ig_b = (const float*)d_in[14];
  const float* W_hg_w = (const float*)d_in[15];
  const float* W_hg_b = (const float*)d_in[16];
  const float* W_io_w = (const float*)d_in[17];
  const float* W_io_b = (const float*)d_in[18];
  const float* W_ho_w = (const float*)d_in[19];
  const float* W_ho_b = (const float*)d_in[20];
  const float* W_co   = (const float*)d_in[21];

  // ws: A bf16 [4096][2048] (16MB) | Bm bf16 [4096][2048] (16MB) | Z bf16 [4096][4096] (32MB)
  unsigned short* Apack = (unsigned short*)d_ws;
  unsigned short* Bpack = Apack + (size_t)BD * KD;
  unsigned short* Zbuf  = Bpack + (size_t)ND * KD;
  float* out = (float*)d_out;

  pack_AB<<<dim3(16384), dim3(256), 0, stream>>>(
      x, h, W_ii_w, W_if_w, W_ig_w, W_io_w, W_hi_w, W_hf_w, W_hg_w, W_ho_w,
      Apack, Bpack);
  gemm_bf16<<<dim3(256), dim3(512), 0, stream>>>(Apack, Bpack, Zbuf);
  lstm_cell<<<dim3(4096), dim3(256), 0, stream>>>(Zbuf, c,
      W_ii_b, W_hi_b, W_if_b, W_hf_b, W_ig_b, W_hg_b, W_io_b, W_ho_b,
      W_ci, W_cf, W_co, out);
}

// Round 5
// 220.606 us; speedup vs baseline: 1.1384x; 1.0613x over previous
//
#include <hip/hip_runtime.h>
#include <hip/hip_bf16.h>

// Problem dims
#define BD 4096   // batch
#define ID 1024   // input dim
#define HD 1024   // hidden dim
#define KD 2048   // I + H  (concatenated GEMM K)
#define ND 4096   // 4*H    (gate-interleaved GEMM N: col n = r*4 + g)

typedef __attribute__((ext_vector_type(8))) __bf16 bf16x8;
typedef __attribute__((ext_vector_type(4))) float f32x4;

static __device__ __forceinline__ unsigned short f2bf(float f) {
  union { float f; unsigned u; } v; v.f = f;
  unsigned u = v.u;
  unsigned r = u + 0x7fffu + ((u >> 16) & 1u);   // round-to-nearest-even
  return (unsigned short)(r >> 16);
}
static __device__ __forceinline__ float bf2f(unsigned short s) {
  union { unsigned u; float f; } v; v.u = ((unsigned)s) << 16;
  return v.f;
}

static __device__ __forceinline__ void gload_lds16(const void* g, void* l) {
  __builtin_amdgcn_global_load_lds(
      (const __attribute__((address_space(1))) void*)g,
      (__attribute__((address_space(3))) void*)l, 16, 0, 0);
}

static __device__ __forceinline__ float fast_sigmoid(float x) {
  return 1.0f / (1.0f + __expf(-x));
}
static __device__ __forceinline__ float fast_tanh(float x) {
  float t = __expf(-2.0f * fabsf(x));
  float r = (1.0f - t) / (1.0f + t);
  return copysignf(r, x);
}

// ---------------- fused pack kernel: f32 -> bf16, A=[x|h], Bm=[Wx|Wh] ----------
// Bm row n corresponds to gate g = n&3 of hidden unit r = n>>2 (gate-interleaved).
__global__ void pack_AB(const float* __restrict__ x, const float* __restrict__ h,
                        const float* __restrict__ wxi, const float* __restrict__ wxf,
                        const float* __restrict__ wxg, const float* __restrict__ wxo,
                        const float* __restrict__ whi, const float* __restrict__ whf,
                        const float* __restrict__ whg, const float* __restrict__ who,
                        unsigned short* __restrict__ A, unsigned short* __restrict__ Bm) {
  if (blockIdx.x < 8192) {
    int idx = blockIdx.x * blockDim.x + threadIdx.x;
    int e = idx << 2;
    int b = e >> 11;
    int k = e & 2047;
    const float* src = (k < ID) ? (x + (size_t)b * ID + k)
                                : (h + (size_t)b * HD + (k - ID));
    float4 v = *reinterpret_cast<const float4*>(src);
    ushort4 o;
    o.x = f2bf(v.x); o.y = f2bf(v.y); o.z = f2bf(v.z); o.w = f2bf(v.w);
    *reinterpret_cast<ushort4*>(A + e) = o;
  } else {
    int idx = (blockIdx.x - 8192) * blockDim.x + threadIdx.x;
    int e = idx << 2;
    int n = e >> 11;
    int k = e & 2047;
    int g = n & 3, r = n >> 2;         // gate-interleaved
    const float* src;
    if (k < ID) {
      src = (g == 0) ? wxi : (g == 1) ? wxf : (g == 2) ? wxg : wxo;
      src += (size_t)r * ID + k;
    } else {
      src = (g == 0) ? whi : (g == 1) ? whf : (g == 2) ? whg : who;
      src += (size_t)r * HD + (k - ID);
    }
    float4 v = *reinterpret_cast<const float4*>(src);
    ushort4 o;
    o.x = f2bf(v.x); o.y = f2bf(v.y); o.z = f2bf(v.z); o.w = f2bf(v.w);
    *reinterpret_cast<ushort4*>(Bm + e) = o;
  }
}

// ---------------- fused GEMM + peephole-LSTM epilogue --------------------------
// z[M][N] = A[M][K] * Bm[N][K]^T, then per (b, r): gates from 4 adjacent cols,
// h/c computed in-block via LDS transpose. 256x256 tile, BK=64, 8 waves (2Mx4N),
// double-buffered swizzled LDS, 4 MFMA phases/tile, single aged vmcnt(0) per
// tile boundary, staging spread over phases 0-2, setprio, XCD swizzle.
__global__ __launch_bounds__(512, 2) void gemm_lstm(
    const unsigned short* __restrict__ A,   // [4096][2048]
    const unsigned short* __restrict__ Bm,  // [4096][2048]
    const float* __restrict__ c,            // [4096][1024]
    const float* __restrict__ bxi, const float* __restrict__ bhi,
    const float* __restrict__ bxf, const float* __restrict__ bhf,
    const float* __restrict__ bxg, const float* __restrict__ bhg,
    const float* __restrict__ bxo, const float* __restrict__ bho,
    const float* __restrict__ pci, const float* __restrict__ pcf,
    const float* __restrict__ pco,
    float* __restrict__ out) {              // h [4096][1024] | c [4096][1024]
  // K-loop uses lds[0..65536) ushorts (A: [2][256][64] at 0, B at 32768).
  // Epilogue reuses as zl[256][264] bf16 (135168 B total).
  __shared__ __attribute__((aligned(16))) unsigned short lds[67584];

  const int tid  = threadIdx.x;     // 0..511
  const int lane = tid & 63;
  const int w    = tid >> 6;        // wave 0..7
  const int wr   = w >> 2;          // 0..1  (wave row: 128 rows)
  const int wc   = w & 3;           // 0..3  (wave col: 64 cols)

  // XCD-aware swizzle: 256 blocks, 8 XCDs, 32 contiguous per XCD (bijective).
  const int bid = blockIdx.x;
  const int swz = (bid & 7) * 32 + (bid >> 3);
  const int m0  = (swz >> 4) * 256;
  const int n0  = (swz & 15) * 256;

  f32x4 acc[8][4];
#pragma unroll
  for (int i = 0; i < 8; ++i)
#pragma unroll
    for (int j = 0; j < 4; ++j)
      acc[i][j] = (f32x4){0.f, 0.f, 0.f, 0.f};

  // per-lane swizzled read offsets (elements); slot = chunk ^ (row&7)
  const int sw  = lane & 7;
  const int rA0 = (wr * 128 + (lane & 15)) * 64;
  const int rB0 = (wc * 64  + (lane & 15)) * 64;
  const int offk0 = (((lane >> 4)    ) ^ sw) * 8;
  const int offk1 = (((lane >> 4) + 4) ^ sw) * 8;

  unsigned short* ldsA = lds;           // [2][256][64]
  unsigned short* ldsB = lds + 32768;   // [2][256][64]

  // QB: all 256 B rows (4 x gload_lds16 per thread)
  auto stageB = [&](int buf, int kt) {
#pragma unroll
    for (int q = 0; q < 4; ++q) {
      int ci  = q * 512 + tid;          // 16B chunk index 0..2047
      int row = ci >> 3;
      int sc  = (ci & 7) ^ (row & 7);   // inverse-swizzled source chunk
      gload_lds16(Bm + (size_t)(n0 + row) * KD + kt + sc * 8,
                  ldsB + buf * 16384 + (q * 512 + w * 64) * 8);
    }
  };
  // QA_p: A rows {p*32..p*32+31} u {128+p*32..} (1 x gload_lds16 per thread)
  auto stageA = [&](int buf, int kt, int p) {
    int half = tid >> 8;                // wave-uniform (w>>2)
    int idx  = tid & 255;
    int row  = half * 128 + p * 32 + (idx >> 3);
    int sc   = (idx & 7) ^ ((idx >> 3) & 7);
    gload_lds16(A + (size_t)(m0 + row) * KD + kt + sc * 8,
                ldsA + buf * 16384 + (half * 1024 + p * 256 + (w & 3) * 64) * 8);
  };

  // prologue: full tile 0
  stageB(0, 0);
  stageA(0, 0, 0);
  stageA(0, 0, 1);
  stageA(0, 0, 2);
  stageA(0, 0, 3);

  bf16x8 bfr[4][2];

  for (int T = 0; T < 32; ++T) {
    const int buf = T & 1;
    const unsigned short* pA = ldsA + buf * 16384;
    const unsigned short* pB = ldsB + buf * 16384;
    const int ktn = (T + 1) * 64;

    // boundary: tile T's 8 loads were all issued during T-1 (>=1 tile old) ->
    // vmcnt(0) is a near-free aged wait, not a drain-of-fresh-issues.
    asm volatile("s_waitcnt vmcnt(0)" ::: "memory");
    __builtin_amdgcn_s_barrier();
    __builtin_amdgcn_sched_barrier(0);

#pragma unroll
    for (int p = 0; p < 4; ++p) {
      if (p == 0) {
#pragma unroll
        for (int ni = 0; ni < 4; ++ni) {
          bfr[ni][0] = *(const bf16x8*)(pB + rB0 + ni * 1024 + offk0);
          bfr[ni][1] = *(const bf16x8*)(pB + rB0 + ni * 1024 + offk1);
        }
      }
      bf16x8 af[2][2];
#pragma unroll
      for (int i = 0; i < 2; ++i) {
        af[i][0] = *(const bf16x8*)(pA + rA0 + (2 * p + i) * 1024 + offk0);
        af[i][1] = *(const bf16x8*)(pA + rA0 + (2 * p + i) * 1024 + offk1);
      }
      // spread next tile's issue over phases 0-2 (>=2-phase aging by boundary)
      if (T < 31) {
        if (p == 0)      { stageB(buf ^ 1, ktn); }
        else if (p == 1) { stageA(buf ^ 1, ktn, 0); stageA(buf ^ 1, ktn, 1); }
        else if (p == 2) { stageA(buf ^ 1, ktn, 2); stageA(buf ^ 1, ktn, 3); }
      }
      __builtin_amdgcn_sched_barrier(0);

      __builtin_amdgcn_s_setprio(1);
#pragma unroll
      for (int i = 0; i < 2; ++i)
#pragma unroll
        for (int ni = 0; ni < 4; ++ni)
#pragma unroll
          for (int kk = 0; kk < 2; ++kk)
            acc[2 * p + i][ni] = __builtin_amdgcn_mfma_f32_16x16x32_bf16(
                af[i][kk], bfr[ni][kk], acc[2 * p + i][ni], 0, 0, 0);
      __builtin_amdgcn_s_setprio(0);

      if (p < 3) __builtin_amdgcn_s_barrier();
    }
  }

  // ---------------- fused epilogue ----------------
  // 1) dump z (bf16) into zl[256][264] (pad 8 -> 4-way write conflicts max)
  unsigned short* zl = lds;
  __builtin_amdgcn_s_barrier();   // all K-loop LDS reads complete
#pragma unroll
  for (int mi = 0; mi < 8; ++mi)
#pragma unroll
    for (int ni = 0; ni < 4; ++ni) {
      const int cl = wc * 64 + ni * 16 + (lane & 15);
#pragma unroll
      for (int q = 0; q < 4; ++q) {
        const int rl = wr * 128 + (lane >> 4) * 4 + mi * 16 + q;
        zl[rl * 264 + cl] = f2bf(acc[mi][ni][q]);
      }
    }
  __builtin_amdgcn_s_barrier();

  // 2) per-thread: fixed r (=tid&63), rows stride 8; all accesses coalesced.
  {
    const int r_loc = tid & 63;
    const int rg    = (n0 >> 2) + r_loc;      // global hidden-unit index
    const float bi_ = bxi[rg] + bhi[rg];
    const float bf_ = bxf[rg] + bhf[rg];
    const float bg_ = bxg[rg] + bhg[rg];
    const float bo_ = bxo[rg] + bho[rg];
    const float pi_ = pci[rg];
    const float pf_ = pcf[rg];
    const float po_ = pco[rg];
#pragma unroll 4
    for (int it = 0; it < 32; ++it) {
      const int rl  = (tid >> 6) + it * 8;    // wave-uniform row
      const int row = m0 + rl;
      ushort4 zv = *(const ushort4*)&zl[rl * 264 + r_loc * 4];
      float cc = c[(size_t)row * HD + rg];
      float vi = bf2f(zv.x) + bi_ + pi_ * cc;
      float vf = bf2f(zv.y) + bf_ + pf_ * cc;
      float vg = bf2f(zv.z) + bg_;
      float vo = bf2f(zv.w) + bo_;
      float ig = fast_sigmoid(vi);
      float fg = fast_sigmoid(vf);
      float gg = fast_tanh(vg);
      float cnext = fg * cc + ig * gg;
      float og = fast_sigmoid(vo + po_ * cnext);
      out[(size_t)row * HD + rg] = og * fast_tanh(cnext);
      out[(size_t)BD * HD + (size_t)row * HD + rg] = cnext;
    }
  }
}

// ---------------- launch -------------------------------------------------------
extern "C" void kernel_launch(void* const* d_in, const int* in_sizes, int n_in,
                              void* d_out, int out_size, void* d_ws, size_t ws_size,
                              hipStream_t stream) {
  const float* x      = (const float*)d_in[0];
  const float* h      = (const float*)d_in[1];
  const float* c      = (const float*)d_in[2];
  const float* W_ii_w = (const float*)d_in[3];
  const float* W_ii_b = (const float*)d_in[4];
  const float* W_hi_w = (const float*)d_in[5];
  const float* W_hi_b = (const float*)d_in[6];
  const float* W_ci   = (const float*)d_in[7];
  const float* W_if_w = (const float*)d_in[8];
  const float* W_if_b = (const float*)d_in[9];
  const float* W_hf_w = (const float*)d_in[10];
  const float* W_hf_b = (const float*)d_in[11];
  const float* W_cf   = (const float*)d_in[12];
  const float* W_ig_w = (const float*)d_in[13];
  const float* W_ig_b = (const float*)d_in[14];
  const float* W_hg_w = (const float*)d_in[15];
  const float* W_hg_b = (const float*)d_in[16];
  const float* W_io_w = (const float*)d_in[17];
  const float* W_io_b = (const float*)d_in[18];
  const float* W_ho_w = (const float*)d_in[19];
  const float* W_ho_b = (const float*)d_in[20];
  const float* W_co   = (const float*)d_in[21];

  // ws: A bf16 [4096][2048] (16MB) | Bm bf16 [4096][2048] (16MB)
  unsigned short* Apack = (unsigned short*)d_ws;
  unsigned short* Bpack = Apack + (size_t)BD * KD;
  float* out = (float*)d_out;

  pack_AB<<<dim3(16384), dim3(256), 0, stream>>>(
      x, h, W_ii_w, W_if_w, W_ig_w, W_io_w, W_hi_w, W_hf_w, W_hg_w, W_ho_w,
      Apack, Bpack);
  gemm_lstm<<<dim3(256), dim3(512), 0, stream>>>(
      Apack, Bpack, c,
      W_ii_b, W_hi_b, W_if_b, W_hf_b, W_ig_b, W_hg_b, W_io_b, W_ho_b,
      W_ci, W_cf, W_co, out);
}

// Round 6
// 218.862 us; speedup vs baseline: 1.1475x; 1.0080x over previous
//
#include <hip/hip_runtime.h>
#include <hip/hip_bf16.h>

// Problem dims
#define BD 4096   // batch
#define ID 1024   // input dim
#define HD 1024   // hidden dim
#define KD 2048   // I + H  (concatenated GEMM K)
#define ND 4096   // 4*H    (gate-interleaved GEMM N: col n = r*4 + g)

typedef __attribute__((ext_vector_type(8))) __bf16 bf16x8;
typedef __attribute__((ext_vector_type(4))) float f32x4;

static __device__ __forceinline__ unsigned short f2bf(float f) {
  union { float f; unsigned u; } v; v.f = f;
  unsigned u = v.u;
  unsigned r = u + 0x7fffu + ((u >> 16) & 1u);   // round-to-nearest-even
  return (unsigned short)(r >> 16);
}
static __device__ __forceinline__ float bf2f(unsigned short s) {
  union { unsigned u; float f; } v; v.u = ((unsigned)s) << 16;
  return v.f;
}

static __device__ __forceinline__ void gload_lds16(const void* g, void* l) {
  __builtin_amdgcn_global_load_lds(
      (const __attribute__((address_space(1))) void*)g,
      (__attribute__((address_space(3))) void*)l, 16, 0, 0);
}

// approx-rcp gate math: v_exp_f32 + v_rcp_f32, ~1e-7 rel err, correct
// saturation (exp->inf => rcp->0).  5 ops vs ~20 for precise-div versions.
static __device__ __forceinline__ float fast_sigmoid(float x) {
  return __builtin_amdgcn_rcpf(1.0f + __expf(-x));
}
static __device__ __forceinline__ float fast_tanh(float x) {
  return 2.0f * __builtin_amdgcn_rcpf(1.0f + __expf(-2.0f * x)) - 1.0f;
}

// ---------------- fused pack kernel: f32 -> bf16, A=[x|h], Bm=[Wx|Wh] ----------
// Bm row n corresponds to gate g = n&3 of hidden unit r = n>>2 (gate-interleaved).
__global__ void pack_AB(const float* __restrict__ x, const float* __restrict__ h,
                        const float* __restrict__ wxi, const float* __restrict__ wxf,
                        const float* __restrict__ wxg, const float* __restrict__ wxo,
                        const float* __restrict__ whi, const float* __restrict__ whf,
                        const float* __restrict__ whg, const float* __restrict__ who,
                        unsigned short* __restrict__ A, unsigned short* __restrict__ Bm) {
  if (blockIdx.x < 8192) {
    int idx = blockIdx.x * blockDim.x + threadIdx.x;
    int e = idx << 2;
    int b = e >> 11;
    int k = e & 2047;
    const float* src = (k < ID) ? (x + (size_t)b * ID + k)
                                : (h + (size_t)b * HD + (k - ID));
    float4 v = *reinterpret_cast<const float4*>(src);
    ushort4 o;
    o.x = f2bf(v.x); o.y = f2bf(v.y); o.z = f2bf(v.z); o.w = f2bf(v.w);
    *reinterpret_cast<ushort4*>(A + e) = o;
  } else {
    int idx = (blockIdx.x - 8192) * blockDim.x + threadIdx.x;
    int e = idx << 2;
    int n = e >> 11;
    int k = e & 2047;
    int g = n & 3, r = n >> 2;         // gate-interleaved
    const float* src;
    if (k < ID) {
      src = (g == 0) ? wxi : (g == 1) ? wxf : (g == 2) ? wxg : wxo;
      src += (size_t)r * ID + k;
    } else {
      src = (g == 0) ? whi : (g == 1) ? whf : (g == 2) ? whg : who;
      src += (size_t)r * HD + (k - ID);
    }
    float4 v = *reinterpret_cast<const float4*>(src);
    ushort4 o;
    o.x = f2bf(v.x); o.y = f2bf(v.y); o.z = f2bf(v.z); o.w = f2bf(v.w);
    *reinterpret_cast<ushort4*>(Bm + e) = o;
  }
}

// ---------------- fused GEMM + peephole-LSTM epilogue --------------------------
// z[M][N] = A[M][K] * Bm[N][K]^T, then per (b, r): gates from 4 adjacent cols,
// h/c computed in-block via LDS transpose. 256x256 tile, BK=64, 8 waves (2Mx4N),
// double-buffered swizzled LDS, ONE vmcnt(0)+barrier per K-tile (loads aged a
// full tile = 64 MFMA before the wait), barrier-free tile body so the compiler
// pipelines ds_read latency under MFMA, setprio clusters, XCD swizzle.
__global__ __launch_bounds__(512, 2) void gemm_lstm(
    const unsigned short* __restrict__ A,   // [4096][2048]
    const unsigned short* __restrict__ Bm,  // [4096][2048]
    const float* __restrict__ c,            // [4096][1024]
    const float* __restrict__ bxi, const float* __restrict__ bhi,
    const float* __restrict__ bxf, const float* __restrict__ bhf,
    const float* __restrict__ bxg, const float* __restrict__ bhg,
    const float* __restrict__ bxo, const float* __restrict__ bho,
    const float* __restrict__ pci, const float* __restrict__ pcf,
    const float* __restrict__ pco,
    float* __restrict__ out) {              // h [4096][1024] | c [4096][1024]
  // K-loop uses lds[0..65536) ushorts (A: [2][256][64] at 0, B at 32768).
  // Epilogue reuses as zl[256][264] bf16 (135168 B total).
  __shared__ __attribute__((aligned(16))) unsigned short lds[67584];

  const int tid  = threadIdx.x;     // 0..511
  const int lane = tid & 63;
  const int w    = tid >> 6;        // wave 0..7
  const int wr   = w >> 2;          // 0..1  (wave row: 128 rows)
  const int wc   = w & 3;           // 0..3  (wave col: 64 cols)

  // XCD-aware swizzle: 256 blocks, 8 XCDs, 32 contiguous per XCD (bijective).
  const int bid = blockIdx.x;
  const int swz = (bid & 7) * 32 + (bid >> 3);
  const int m0  = (swz >> 4) * 256;
  const int n0  = (swz & 15) * 256;

  f32x4 acc[8][4];
#pragma unroll
  for (int i = 0; i < 8; ++i)
#pragma unroll
    for (int j = 0; j < 4; ++j)
      acc[i][j] = (f32x4){0.f, 0.f, 0.f, 0.f};

  // per-lane swizzled read offsets (elements); slot = chunk ^ (row&7)
  const int sw  = lane & 7;
  const int rA0 = (wr * 128 + (lane & 15)) * 64;
  const int rB0 = (wc * 64  + (lane & 15)) * 64;
  const int offk0 = (((lane >> 4)    ) ^ sw) * 8;
  const int offk1 = (((lane >> 4) + 4) ^ sw) * 8;

  unsigned short* ldsA = lds;           // [2][256][64]
  unsigned short* ldsB = lds + 32768;   // [2][256][64]

  // QB: all 256 B rows (4 x gload_lds16 per thread)
  auto stageB = [&](int buf, int kt) {
#pragma unroll
    for (int q = 0; q < 4; ++q) {
      int ci  = q * 512 + tid;          // 16B chunk index 0..2047
      int row = ci >> 3;
      int sc  = (ci & 7) ^ (row & 7);   // inverse-swizzled source chunk
      gload_lds16(Bm + (size_t)(n0 + row) * KD + kt + sc * 8,
                  ldsB + buf * 16384 + (q * 512 + w * 64) * 8);
    }
  };
  // QA_p: A rows {p*32..p*32+31} u {128+p*32..} (1 x gload_lds16 per thread)
  auto stageA = [&](int buf, int kt, int p) {
    int half = tid >> 8;                // wave-uniform (w>>2)
    int idx  = tid & 255;
    int row  = half * 128 + p * 32 + (idx >> 3);
    int sc   = (idx & 7) ^ ((idx >> 3) & 7);
    gload_lds16(A + (size_t)(m0 + row) * KD + kt + sc * 8,
                ldsA + buf * 16384 + (half * 1024 + p * 256 + (w & 3) * 64) * 8);
  };

  // prologue: full tile 0
  stageB(0, 0);
  stageA(0, 0, 0);
  stageA(0, 0, 1);
  stageA(0, 0, 2);
  stageA(0, 0, 3);

  for (int T = 0; T < 32; ++T) {
    const int buf = T & 1;
    const unsigned short* pA = ldsA + buf * 16384;
    const unsigned short* pB = ldsB + buf * 16384;
    const int ktn = (T + 1) * 64;

    // boundary: tile T's 8 loads were all issued during T-1 (aged ~64 MFMA) ->
    // vmcnt(0) is a near-free aged wait, not a drain-of-fresh-issues.
    asm volatile("s_waitcnt vmcnt(0)" ::: "memory");
    __builtin_amdgcn_s_barrier();

    // issue next tile's stages first so they age the longest
    if (T < 31) {
      stageB(buf ^ 1, ktn);
      stageA(buf ^ 1, ktn, 0);
      stageA(buf ^ 1, ktn, 1);
      stageA(buf ^ 1, ktn, 2);
      stageA(buf ^ 1, ktn, 3);
    }
    __builtin_amdgcn_sched_barrier(0);

    // barrier-free tile body: 16 ds_read_b128 + 64 MFMA, compiler-pipelined
    bf16x8 bfr[4][2];
#pragma unroll
    for (int ni = 0; ni < 4; ++ni) {
      bfr[ni][0] = *(const bf16x8*)(pB + rB0 + ni * 1024 + offk0);
      bfr[ni][1] = *(const bf16x8*)(pB + rB0 + ni * 1024 + offk1);
    }
#pragma unroll
    for (int p = 0; p < 4; ++p) {
      bf16x8 af[2][2];
#pragma unroll
      for (int i = 0; i < 2; ++i) {
        af[i][0] = *(const bf16x8*)(pA + rA0 + (2 * p + i) * 1024 + offk0);
        af[i][1] = *(const bf16x8*)(pA + rA0 + (2 * p + i) * 1024 + offk1);
      }
      __builtin_amdgcn_s_setprio(1);
#pragma unroll
      for (int i = 0; i < 2; ++i)
#pragma unroll
        for (int ni = 0; ni < 4; ++ni)
#pragma unroll
          for (int kk = 0; kk < 2; ++kk)
            acc[2 * p + i][ni] = __builtin_amdgcn_mfma_f32_16x16x32_bf16(
                af[i][kk], bfr[ni][kk], acc[2 * p + i][ni], 0, 0, 0);
      __builtin_amdgcn_s_setprio(0);
    }
  }

  // ---------------- fused epilogue ----------------
  // 1) dump z (bf16) into zl[256][264]
  unsigned short* zl = lds;
  __builtin_amdgcn_s_barrier();   // all K-loop LDS reads complete
#pragma unroll
  for (int mi = 0; mi < 8; ++mi)
#pragma unroll
    for (int ni = 0; ni < 4; ++ni) {
      const int cl = wc * 64 + ni * 16 + (lane & 15);
#pragma unroll
      for (int q = 0; q < 4; ++q) {
        const int rl = wr * 128 + (lane >> 4) * 4 + mi * 16 + q;
        zl[rl * 264 + cl] = f2bf(acc[mi][ni][q]);
      }
    }
  __builtin_amdgcn_s_barrier();

  // 2) per-thread: fixed r (=tid&63), rows stride 8; all accesses coalesced.
  {
    const int r_loc = tid & 63;
    const int rg    = (n0 >> 2) + r_loc;      // global hidden-unit index
    const float bi_ = bxi[rg] + bhi[rg];
    const float bf_ = bxf[rg] + bhf[rg];
    const float bg_ = bxg[rg] + bhg[rg];
    const float bo_ = bxo[rg] + bho[rg];
    const float pi_ = pci[rg];
    const float pf_ = pcf[rg];
    const float po_ = pco[rg];
#pragma unroll 4
    for (int it = 0; it < 32; ++it) {
      const int rl  = (tid >> 6) + it * 8;    // wave-uniform row
      const int row = m0 + rl;
      ushort4 zv = *(const ushort4*)&zl[rl * 264 + r_loc * 4];
      float cc = c[(size_t)row * HD + rg];
      float vi = bf2f(zv.x) + bi_ + pi_ * cc;
      float vf = bf2f(zv.y) + bf_ + pf_ * cc;
      float vg = bf2f(zv.z) + bg_;
      float vo = bf2f(zv.w) + bo_;
      float ig = fast_sigmoid(vi);
      float fg = fast_sigmoid(vf);
      float gg = fast_tanh(vg);
      float cnext = fg * cc + ig * gg;
      float og = fast_sigmoid(vo + po_ * cnext);
      out[(size_t)row * HD + rg] = og * fast_tanh(cnext);
      out[(size_t)BD * HD + (size_t)row * HD + rg] = cnext;
    }
  }
}

// ---------------- launch -------------------------------------------------------
extern "C" void kernel_launch(void* const* d_in, const int* in_sizes, int n_in,
                              void* d_out, int out_size, void* d_ws, size_t ws_size,
                              hipStream_t stream) {
  const float* x      = (const float*)d_in[0];
  const float* h      = (const float*)d_in[1];
  const float* c      = (const float*)d_in[2];
  const float* W_ii_w = (const float*)d_in[3];
  const float* W_ii_b = (const float*)d_in[4];
  const float* W_hi_w = (const float*)d_in[5];
  const float* W_hi_b = (const float*)d_in[6];
  const float* W_ci   = (const float*)d_in[7];
  const float* W_if_w = (const float*)d_in[8];
  const float* W_if_b = (const float*)d_in[9];
  const float* W_hf_w = (const float*)d_in[10];
  const float* W_hf_b = (const float*)d_in[11];
  const float* W_cf   = (const float*)d_in[12];
  const float* W_ig_w = (const float*)d_in[13];
  const float* W_ig_b = (const float*)d_in[14];
  const float* W_hg_w = (const float*)d_in[15];
  const float* W_hg_b = (const float*)d_in[16];
  const float* W_io_w = (const float*)d_in[17];
  const float* W_io_b = (const float*)d_in[18];
  const float* W_ho_w = (const float*)d_in[19];
  const float* W_ho_b = (const float*)d_in[20];
  const float* W_co   = (const float*)d_in[21];

  // ws: A bf16 [4096][2048] (16MB) | Bm bf16 [4096][2048] (16MB)
  unsigned short* Apack = (unsigned short*)d_ws;
  unsigned short* Bpack = Apack + (size_t)BD * KD;
  float* out = (float*)d_out;

  pack_AB<<<dim3(16384), dim3(256), 0, stream>>>(
      x, h, W_ii_w, W_if_w, W_ig_w, W_io_w, W_hi_w, W_hf_w, W_hg_w, W_ho_w,
      Apack, Bpack);
  gemm_lstm<<<dim3(256), dim3(512), 0, stream>>>(
      Apack, Bpack, c,
      W_ii_b, W_hi_b, W_if_b, W_hf_b, W_ig_b, W_hg_b, W_io_b, W_ho_b,
      W_ci, W_cf, W_co, out);
}